// Round 7
// baseline (343.706 us; speedup 1.0000x reference)
//
#include <hip/hip_runtime.h>
#include <hip/hip_bf16.h>

#define B_ 8
#define C_ 512
#define L_ 2048
#define G_ 32

typedef __attribute__((ext_vector_type(8))) short bf16x8;
typedef __attribute__((ext_vector_type(4))) float f32x4;

__device__ __forceinline__ float b2f(short h) {
    union { unsigned u; float f; } c; c.u = ((unsigned)(unsigned short)h) << 16; return c.f;
}
__device__ __forceinline__ short f2b(float f) {
    union { float f; unsigned u; } c; c.f = f;
    unsigned r = (c.u + 0x7FFFu + ((c.u >> 16) & 1u)) >> 16;
    return (short)r;
}

__device__ __forceinline__ void load_lds16(const void* g, void* s) {
    __builtin_amdgcn_global_load_lds(
        (const __attribute__((address_space(1))) void*)g,
        (__attribute__((address_space(3))) void*)s, 16, 0, 0);
}

__global__ __launch_bounds__(256) void zero_f32(float* __restrict__ p) {
    p[(size_t)blockIdx.x * 256 + threadIdx.x] = 0.f;
}

// -------- convert 4 fp32 512x512 weights to bf16, concatenated --------
__global__ __launch_bounds__(256) void cvt_w(
    const float* __restrict__ a, const float* __restrict__ b,
    const float* __restrict__ c, const float* __restrict__ d,
    short* __restrict__ o)
{
    const float* src = (blockIdx.y == 0) ? a : (blockIdx.y == 1) ? b
                     : (blockIdx.y == 2) ? c : d;
    short* dst = o + (size_t)blockIdx.y * (C_ * C_);
    int i = (blockIdx.x * 256 + threadIdx.x) * 4;
    float4 v = *(const float4*)(src + i);
    short4 r;
    r.x = f2b(v.x); r.y = f2b(v.y); r.z = f2b(v.z); r.w = f2b(v.w);
    *(short4*)(dst + i) = r;
}

// -------- GroupNorm + transpose: x[b,c,l] fp32 -> h_t[b,l,c] bf16 --------
__global__ __launch_bounds__(256) void groupnorm_tr(
    const float* __restrict__ x, const float* __restrict__ gamma,
    const float* __restrict__ beta, short* __restrict__ h_t)
{
    int bg = blockIdx.x;
    int b = bg >> 5, g = bg & 31;
    const float* xg = x + ((size_t)b * C_ + (size_t)g * 16) * L_;  // 32768 floats
    int t = threadIdx.x;
    float s = 0.f, ss = 0.f;
    for (int i = t; i < 8192; i += 256) {
        float4 v = ((const float4*)xg)[i];
        s  += v.x + v.y + v.z + v.w;
        ss += v.x * v.x + v.y * v.y + v.z * v.z + v.w * v.w;
    }
    #pragma unroll
    for (int o = 32; o > 0; o >>= 1) { s += __shfl_down(s, o); ss += __shfl_down(ss, o); }
    __shared__ float rs[4], rss[4], stats[2], gam[16], bet[16];
    int wave = t >> 6, lane = t & 63;
    if (lane == 0) { rs[wave] = s; rss[wave] = ss; }
    if (t < 16) { gam[t] = gamma[g * 16 + t]; bet[t] = beta[g * 16 + t]; }
    __syncthreads();
    if (t == 0) {
        float S = rs[0] + rs[1] + rs[2] + rs[3];
        float SS = rss[0] + rss[1] + rss[2] + rss[3];
        float mean = S * (1.f / 32768.f);
        float var = SS * (1.f / 32768.f) - mean * mean;
        stats[0] = mean; stats[1] = rsqrtf(var + 1e-5f);
    }
    __syncthreads();
    float mean = stats[0], rstd = stats[1];
    short* ho = h_t + (size_t)b * L_ * C_ + (size_t)g * 16;
    for (int i = t; i < 32768; i += 256) {
        int cl = i & 15, l = i >> 4;
        float xv = xg[cl * L_ + l];
        float hv = (xv - mean) * rstd * gam[cl] + bet[cl];
        ho[(size_t)l * C_ + cl] = f2b(hv);
    }
}

// -------- generic bt-GEMM, BK=64, XOR-swizzled LDS, double-buffered --------
// C[m,n] = alpha * sum_k A[m,k]*Bt[n,k]  (+bias +resid +exp/rowsum +rowdiv)
// BIAS_MODE: 0 none, 1 bias[n], 2 bias[m], 3 split-n (bias/bias2)
// EXPSUM: store exp(acc*alpha) and atomicAdd fp32 row sums into rowsum[bz*L_+m]
// ROWDIV: multiply acc by 1/rowsum[bz*L_+m]
template<int BN, int BIAS_MODE, bool RESID, bool OUTF32, bool EXPSUM, bool ROWDIV>
__global__ __launch_bounds__(256) void gemm_bt(
    const short* __restrict__ A, const short* __restrict__ Bt,
    void* __restrict__ Co, const float* __restrict__ bias,
    const float* __restrict__ bias2, const float* __restrict__ resid,
    float* __restrict__ rowsum,
    int N, int K, int lda, int ldb, int ldc,
    long sA, long sB, long sC, float alpha)
{
    constexpr int MT = (BN == 128) ? 4 : 2;
    __shared__ __align__(16) short As[2 * 128 * 64];
    __shared__ __align__(16) short Bs[2 * BN * 64];

    int nbx = gridDim.x, nby = gridDim.y, nbz = gridDim.z;
    int lin = blockIdx.x + nbx * (blockIdx.y + nby * blockIdx.z);
    int total = nbx * nby * nbz;
    int bx, by, bz;
    if ((total & 7) == 0) {
        int chunk = total >> 3;
        int logical = (lin & 7) * chunk + (lin >> 3);
        bx = logical % nbx; int t2 = logical / nbx; by = t2 % nby; bz = t2 / nby;
    } else { bx = blockIdx.x; by = blockIdx.y; bz = blockIdx.z; }

    const short* Ab = A + (size_t)bz * sA;
    const short* Bb = Bt + (size_t)bz * sB;
    int m0 = by * 128, n0 = bx * BN;
    int t = threadIdx.x, lane = t & 63;
    int wave = t >> 6;
    int wm = (BN == 128) ? (wave >> 1) : wave;
    int wn = (BN == 128) ? (wave & 1) : 0;

    f32x4 acc[MT][4] = {};

    // staging: LDS slot (row, chunk cs) <- global (row, cs ^ (row&7)), 16B chunks
    int rs_ = t >> 3, cs_ = t & 7;
    int gcol = ((cs_ ^ (rs_ & 7)) << 3);                  // shorts
    const short* gA = Ab + (size_t)(m0 + rs_) * lda + gcol;
    const short* gB = Bb + (size_t)(n0 + rs_) * ldb + gcol;
    int fr = lane & 15, fq = lane >> 4;
    // ds_read chunk for (row, kk): ((kk<<2)|fq) ^ (fr&7)
    int ch0 = (fq ^ (fr & 7)) << 3;                       // kk=0, shorts
    int ch1 = ((4 | fq) ^ (fr & 7)) << 3;                 // kk=1

    // prologue: stage tile 0 into buffer 0
    #pragma unroll
    for (int i = 0; i < 4; i++)
        load_lds16(gA + (size_t)(32 * i) * lda, As + i * 2048 + t * 8);
    #pragma unroll
    for (int i = 0; i < BN / 32; i++)
        load_lds16(gB + (size_t)(32 * i) * ldb, Bs + i * 2048 + t * 8);

    int cur = 0;
    for (int k0 = 0; k0 < K; k0 += 64) {
        __syncthreads();   // drains loads into buf[cur] (issued one full iter ago)
        if (k0 + 64 < K) {
            const short* pA = gA + k0 + 64;
            const short* pB = gB + k0 + 64;
            short* dA = As + (cur ^ 1) * (128 * 64);
            short* dB = Bs + (cur ^ 1) * (BN * 64);
            #pragma unroll
            for (int i = 0; i < 4; i++)
                load_lds16(pA + (size_t)(32 * i) * lda, dA + i * 2048 + t * 8);
            #pragma unroll
            for (int i = 0; i < BN / 32; i++)
                load_lds16(pB + (size_t)(32 * i) * ldb, dB + i * 2048 + t * 8);
        }
        const short* Ac = As + cur * (128 * 64);
        const short* Bc = Bs + cur * (BN * 64);
        #pragma unroll
        for (int kk = 0; kk < 2; kk++) {
            int ch = kk ? ch1 : ch0;
            bf16x8 af[MT], bfr[4];
            #pragma unroll
            for (int i = 0; i < MT; i++) {
                int R = (BN == 128 ? wm * 64 : wm * 32) + i * 16 + fr;
                af[i] = *(const bf16x8*)(Ac + R * 64 + ch);
            }
            #pragma unroll
            for (int j = 0; j < 4; j++) {
                int R = (BN == 128 ? wn * 64 : 0) + j * 16 + fr;
                bfr[j] = *(const bf16x8*)(Bc + R * 64 + ch);
            }
            #pragma unroll
            for (int mt = 0; mt < MT; mt++)
                #pragma unroll
                for (int nt = 0; nt < 4; nt++)
                    acc[mt][nt] = __builtin_amdgcn_mfma_f32_16x16x32_bf16(
                        af[mt], bfr[nt], acc[mt][nt], 0, 0, 0);
        }
        cur ^= 1;
    }

    size_t cb = (size_t)bz * sC;
    int crow = (lane >> 4) * 4;
    int wrow = (BN == 128 ? wm * 64 : wm * 32);
    float psum[MT][4];
    float inv[MT][4];
    if (EXPSUM) {
        #pragma unroll
        for (int mt = 0; mt < MT; mt++)
            #pragma unroll
            for (int r = 0; r < 4; r++) psum[mt][r] = 0.f;
    }
    if (ROWDIV) {
        #pragma unroll
        for (int mt = 0; mt < MT; mt++)
            #pragma unroll
            for (int r = 0; r < 4; r++) {
                int m = m0 + wrow + mt * 16 + crow + r;
                inv[mt][r] = 1.f / rowsum[(size_t)bz * L_ + m];
            }
    }
    #pragma unroll
    for (int mt = 0; mt < MT; mt++) {
        #pragma unroll
        for (int nt = 0; nt < 4; nt++) {
            int n = n0 + (BN == 128 ? wn * 64 : 0) + nt * 16 + fr;
            float bn = 0.f;
            if (BIAS_MODE == 1) bn = bias[n];
            if (BIAS_MODE == 3) bn = (n < 512) ? bias[n] : bias2[n - 512];
            #pragma unroll
            for (int r = 0; r < 4; r++) {
                int m = m0 + wrow + mt * 16 + crow + r;
                float v = acc[mt][nt][r] * alpha;
                if (EXPSUM) { v = __expf(v); psum[mt][r] += v; }
                if (ROWDIV) v *= inv[mt][r];
                if (BIAS_MODE == 1 || BIAS_MODE == 3) v += bn;
                if (BIAS_MODE == 2) v += bias[m];
                size_t idx = cb + (size_t)m * ldc + n;
                if (RESID) v += resid[idx];
                if (OUTF32) ((float*)Co)[idx] = v;
                else        ((short*)Co)[idx] = f2b(v);
            }
        }
    }
    if (EXPSUM) {
        #pragma unroll
        for (int mt = 0; mt < MT; mt++)
            #pragma unroll
            for (int r = 0; r < 4; r++) {
                float s = psum[mt][r];
                s += __shfl_xor(s, 1); s += __shfl_xor(s, 2);
                s += __shfl_xor(s, 4); s += __shfl_xor(s, 8);
                if ((lane & 15) == 0) {
                    int m = m0 + wrow + mt * 16 + crow + r;
                    atomicAdd(rowsum + (size_t)bz * L_ + m, s);
                }
            }
    }
}

extern "C" void kernel_launch(void* const* d_in, const int* in_sizes, int n_in,
                              void* d_out, int out_size, void* d_ws, size_t ws_size,
                              hipStream_t stream)
{
    const float* x     = (const float*)d_in[0];
    const float* gamma = (const float*)d_in[1];
    const float* beta  = (const float*)d_in[2];
    const float* Wq    = (const float*)d_in[3];
    const float* bq    = (const float*)d_in[4];
    const float* Wk    = (const float*)d_in[5];
    const float* bk    = (const float*)d_in[6];
    const float* Wv    = (const float*)d_in[7];
    const float* bv    = (const float*)d_in[8];
    const float* Wo    = (const float*)d_in[9];
    const float* bo    = (const float*)d_in[10];
    float* out = (float*)d_out;

    const size_t MiB = 1024 * 1024;
    const size_t CC = (size_t)C_ * C_;
    const size_t LC = (size_t)L_ * C_;             // 1M elems (2 MiB bf16)
    const size_t LL = (size_t)L_ * L_;             // 4M elems (8 MiB bf16)
    const size_t wbytes = 4 * CC * sizeof(short);  // 2 MiB

    // per batch: h_t 2 + qk_t 4 + v 2 + S 8 MiB + rowsum 8 KiB
    const size_t perb = 16 * MiB + L_ * sizeof(float);
    int nb = 1;
    for (int c = 8; c >= 1; c >>= 1)
        if (ws_size >= wbytes + (size_t)c * perb) { nb = c; break; }

    short* wq_b = (short*)d_ws;       // rows 0-511 Wq, 512-1023 Wk (contiguous)
    short* wv_b = wq_b + 2 * CC;
    short* wo_b = wv_b + CC;
    short* h_t  = wo_b + CC;
    short* qk_t = h_t + (size_t)nb * LC;
    short* v_   = qk_t + (size_t)nb * 2 * LC;
    short* S    = v_  + (size_t)nb * LC;
    float* rsum = (float*)(S + (size_t)nb * LL);
    short* a_t  = h_t;                              // h_t dead after v GEMM

    const long sLC = (long)LC;
    const long sLL = (long)LL;
    const float scale = 0.044194173824159216f;      // 1/sqrt(512)

    cvt_w<<<dim3(C_ * C_ / 1024, 4), 256, 0, stream>>>(Wq, Wk, Wv, Wo, wq_b);

    for (int b0 = 0; b0 < B_; b0 += nb) {
        const float* xb = x + (size_t)b0 * LC;
        float* outb = out + (size_t)b0 * LC;

        zero_f32<<<dim3(nb * L_ / 256), 256, 0, stream>>>(rsum);
        groupnorm_tr<<<dim3(nb * G_), 256, 0, stream>>>(xb, gamma, beta, h_t);

        // qk_t[l, 0..1023] = h_t[l,:]·[Wq;Wk]^T + [bq;bk]
        gemm_bt<128, 3, false, false, false, false><<<dim3(8, 16, nb), 256, 0, stream>>>(
            h_t, wq_b, qk_t, bq, bk, nullptr, nullptr,
            1024, 512, 512, 512, 1024, sLC, 0, 2 * sLC, 1.f);
        // v[c,l] = Wv·h^T + bv
        gemm_bt<64, 2, false, false, false, false><<<dim3(32, 4, nb), 256, 0, stream>>>(
            wv_b, h_t, v_, bv, nullptr, nullptr, nullptr,
            2048, 512, 512, 512, 2048, 0, sLC, sLC, 1.f);
        // P~[i,j] = exp(scale * q[i,:]·k[j,:]);  rowsum[i] += partials
        gemm_bt<128, 0, false, false, true, false><<<dim3(16, 16, nb), 256, 0, stream>>>(
            qk_t, qk_t + 512, S, nullptr, nullptr, nullptr, rsum,
            2048, 512, 1024, 1024, 2048, 2 * sLC, 2 * sLC, sLL, scale);
        // a_t[i,c] = (sum_j P~[i,j] v[c,j]) / rowsum[i]
        gemm_bt<64, 0, false, false, false, true><<<dim3(8, 16, nb), 256, 0, stream>>>(
            S, v_, a_t, nullptr, nullptr, nullptr, rsum,
            512, 2048, 2048, 2048, 512, sLL, sLC, sLC, 1.f);
        // out[c,l] = x[c,l] + bo[c] + Wo·a^T   (fp32 out)
        gemm_bt<64, 2, true, true, false, false><<<dim3(32, 4, nb), 256, 0, stream>>>(
            wo_b, a_t, outb, bo, nullptr, xb, nullptr,
            2048, 512, 512, 512, 2048, 0, sLC, sLC, 1.f);
    }
}

// Round 8
// 313.307 us; speedup vs baseline: 1.0970x; 1.0970x over previous
//
#include <hip/hip_runtime.h>
#include <hip/hip_bf16.h>

#define B_ 8
#define C_ 512
#define L_ 2048
#define G_ 32

typedef __attribute__((ext_vector_type(8))) short bf16x8;
typedef __attribute__((ext_vector_type(4))) float f32x4;

__device__ __forceinline__ float b2f(short h) {
    union { unsigned u; float f; } c; c.u = ((unsigned)(unsigned short)h) << 16; return c.f;
}
__device__ __forceinline__ short f2b(float f) {
    union { float f; unsigned u; } c; c.f = f;
    unsigned r = (c.u + 0x7FFFu + ((c.u >> 16) & 1u)) >> 16;
    return (short)r;
}

__device__ __forceinline__ void load_lds16(const void* g, void* s) {
    __builtin_amdgcn_global_load_lds(
        (const __attribute__((address_space(1))) void*)g,
        (__attribute__((address_space(3))) void*)s, 16, 0, 0);
}

__global__ __launch_bounds__(256) void zero_f32(float* __restrict__ p) {
    p[(size_t)blockIdx.x * 256 + threadIdx.x] = 0.f;
}

// -------- convert 4 fp32 512x512 weights to bf16, concatenated --------
__global__ __launch_bounds__(256) void cvt_w(
    const float* __restrict__ a, const float* __restrict__ b,
    const float* __restrict__ c, const float* __restrict__ d,
    short* __restrict__ o)
{
    const float* src = (blockIdx.y == 0) ? a : (blockIdx.y == 1) ? b
                     : (blockIdx.y == 2) ? c : d;
    short* dst = o + (size_t)blockIdx.y * (C_ * C_);
    int i = (blockIdx.x * 256 + threadIdx.x) * 4;
    float4 v = *(const float4*)(src + i);
    short4 r;
    r.x = f2b(v.x); r.y = f2b(v.y); r.z = f2b(v.z); r.w = f2b(v.w);
    *(short4*)(dst + i) = r;
}

// -------- GroupNorm + transpose: x[b,c,l] fp32 -> h_t[b,l,c] bf16 --------
__global__ __launch_bounds__(256) void groupnorm_tr(
    const float* __restrict__ x, const float* __restrict__ gamma,
    const float* __restrict__ beta, short* __restrict__ h_t)
{
    int bg = blockIdx.x;
    int b = bg >> 5, g = bg & 31;
    const float* xg = x + ((size_t)b * C_ + (size_t)g * 16) * L_;  // 32768 floats
    int t = threadIdx.x;
    float s = 0.f, ss = 0.f;
    for (int i = t; i < 8192; i += 256) {
        float4 v = ((const float4*)xg)[i];
        s  += v.x + v.y + v.z + v.w;
        ss += v.x * v.x + v.y * v.y + v.z * v.z + v.w * v.w;
    }
    #pragma unroll
    for (int o = 32; o > 0; o >>= 1) { s += __shfl_down(s, o); ss += __shfl_down(ss, o); }
    __shared__ float rs[4], rss[4], stats[2], gam[16], bet[16];
    int wave = t >> 6, lane = t & 63;
    if (lane == 0) { rs[wave] = s; rss[wave] = ss; }
    if (t < 16) { gam[t] = gamma[g * 16 + t]; bet[t] = beta[g * 16 + t]; }
    __syncthreads();
    if (t == 0) {
        float S = rs[0] + rs[1] + rs[2] + rs[3];
        float SS = rss[0] + rss[1] + rss[2] + rss[3];
        float mean = S * (1.f / 32768.f);
        float var = SS * (1.f / 32768.f) - mean * mean;
        stats[0] = mean; stats[1] = rsqrtf(var + 1e-5f);
    }
    __syncthreads();
    float mean = stats[0], rstd = stats[1];
    short* ho = h_t + (size_t)b * L_ * C_ + (size_t)g * 16;
    for (int i = t; i < 32768; i += 256) {
        int cl = i & 15, l = i >> 4;
        float xv = xg[cl * L_ + l];
        float hv = (xv - mean) * rstd * gam[cl] + bet[cl];
        ho[(size_t)l * C_ + cl] = f2b(hv);
    }
}

// -------- bt-GEMM: BM x 128 tile, BK=64, XOR-swizzled LDS, single-buffer --------
// BM=128 -> 256 thr (4 waves, 2x2), BM=256 -> 512 thr (8 waves, 4x2); wave tile 64x64.
// C[m,n] = alpha * sum_k A[m,k]*Bt[n,k]  (+bias +resid +exp/rowsum +rowdiv)
// BIAS_MODE: 0 none, 2 bias[m], 3 split-n (n<512: bias[n], else bias2[n-512])
template<int BM, int BIAS_MODE, bool RESID, bool OUTF32, bool EXPSUM, bool ROWDIV>
__global__ __launch_bounds__(BM * 2) void gemm_bt(
    const short* __restrict__ A, const short* __restrict__ Bt,
    void* __restrict__ Co, const float* __restrict__ bias,
    const float* __restrict__ bias2, const float* __restrict__ resid,
    float* __restrict__ rowsum,
    int N, int K, int lda, int ldb, int ldc,
    long sA, long sB, long sC, float alpha)
{
    constexpr int T = BM * 2;          // threads
    constexpr int RPP = T / 8;         // rows staged per pass (8 thr/row)
    __shared__ __align__(16) short As[BM * 64];
    __shared__ __align__(16) short Bs[128 * 64];

    int nbx = gridDim.x, nby = gridDim.y, nbz = gridDim.z;
    int lin = blockIdx.x + nbx * (blockIdx.y + nby * blockIdx.z);
    int total = nbx * nby * nbz;
    int bx, by, bz;
    if ((total & 7) == 0) {
        int chunk = total >> 3;
        int logical = (lin & 7) * chunk + (lin >> 3);
        bx = logical % nbx; int t2 = logical / nbx; by = t2 % nby; bz = t2 / nby;
    } else { bx = blockIdx.x; by = blockIdx.y; bz = blockIdx.z; }

    const short* Ab = A + (size_t)bz * sA;
    const short* Bb = Bt + (size_t)bz * sB;
    int m0 = by * BM, n0 = bx * 128;
    int t = threadIdx.x, lane = t & 63;
    int wave = t >> 6;
    int wm = wave >> 1, wn = wave & 1;   // wave grid (BM/64) x 2

    f32x4 acc[4][4] = {};

    // staging: LDS slot (row, chunk cs) <- global (row, cs ^ (row&7)), 16B chunks
    int rs_ = t >> 3, cs_ = t & 7;
    int gcol = ((cs_ ^ (rs_ & 7)) << 3);                  // shorts
    const short* gA = Ab + (size_t)(m0 + rs_) * lda + gcol;
    const short* gB = Bb + (size_t)(n0 + rs_) * ldb + gcol;
    int fr = lane & 15, fq = lane >> 4;
    int ch0 = (fq ^ (fr & 7)) << 3;                       // kk=0 chunk, shorts
    int ch1 = ((4 | fq) ^ (fr & 7)) << 3;                 // kk=1

    for (int k0 = 0; k0 < K; k0 += 64) {
        __syncthreads();
        #pragma unroll
        for (int i = 0; i < BM / RPP; i++)
            load_lds16(gA + (size_t)(RPP * i) * lda, As + i * (RPP * 64) + t * 8);
        #pragma unroll
        for (int i = 0; i < 128 / RPP; i++)
            load_lds16(gB + (size_t)(RPP * i) * ldb, Bs + i * (RPP * 64) + t * 8);
        gA += 64; gB += 64;
        __syncthreads();
        #pragma unroll
        for (int kk = 0; kk < 2; kk++) {
            int ch = kk ? ch1 : ch0;
            bf16x8 af[4], bfr[4];
            #pragma unroll
            for (int i = 0; i < 4; i++) {
                int R = wm * 64 + i * 16 + fr;
                af[i] = *(const bf16x8*)(As + R * 64 + ch);
            }
            #pragma unroll
            for (int j = 0; j < 4; j++) {
                int R = wn * 64 + j * 16 + fr;
                bfr[j] = *(const bf16x8*)(Bs + R * 64 + ch);
            }
            #pragma unroll
            for (int mt = 0; mt < 4; mt++)
                #pragma unroll
                for (int nt = 0; nt < 4; nt++)
                    acc[mt][nt] = __builtin_amdgcn_mfma_f32_16x16x32_bf16(
                        af[mt], bfr[nt], acc[mt][nt], 0, 0, 0);
        }
    }

    size_t cb = (size_t)bz * sC;
    int crow = (lane >> 4) * 4;
    int wrow = wm * 64;
    float psum[4][4];
    float inv[4][4];
    if (EXPSUM) {
        #pragma unroll
        for (int mt = 0; mt < 4; mt++)
            #pragma unroll
            for (int r = 0; r < 4; r++) psum[mt][r] = 0.f;
    }
    if (ROWDIV) {
        #pragma unroll
        for (int mt = 0; mt < 4; mt++)
            #pragma unroll
            for (int r = 0; r < 4; r++) {
                int m = m0 + wrow + mt * 16 + crow + r;
                inv[mt][r] = 1.f / rowsum[(size_t)bz * L_ + m];
            }
    }
    #pragma unroll
    for (int mt = 0; mt < 4; mt++) {
        #pragma unroll
        for (int nt = 0; nt < 4; nt++) {
            int n = n0 + wn * 64 + nt * 16 + fr;
            float bn = 0.f;
            if (BIAS_MODE == 3) bn = (n < 512) ? bias[n] : bias2[n - 512];
            #pragma unroll
            for (int r = 0; r < 4; r++) {
                int m = m0 + wrow + mt * 16 + crow + r;
                float v = acc[mt][nt][r] * alpha;
                if (EXPSUM) { v = __expf(v); psum[mt][r] += v; }
                if (ROWDIV) v *= inv[mt][r];
                if (BIAS_MODE == 3) v += bn;
                if (BIAS_MODE == 2) v += bias[m];
                size_t idx = cb + (size_t)m * ldc + n;
                if (RESID) v += resid[idx];
                if (OUTF32) ((float*)Co)[idx] = v;
                else        ((short*)Co)[idx] = f2b(v);
            }
        }
    }
    if (EXPSUM) {
        #pragma unroll
        for (int mt = 0; mt < 4; mt++)
            #pragma unroll
            for (int r = 0; r < 4; r++) {
                float s = psum[mt][r];
                s += __shfl_xor(s, 1); s += __shfl_xor(s, 2);
                s += __shfl_xor(s, 4); s += __shfl_xor(s, 8);
                if ((lane & 15) == 0) {
                    int m = m0 + wrow + mt * 16 + crow + r;
                    atomicAdd(rowsum + (size_t)bz * L_ + m, s);
                }
            }
    }
}

extern "C" void kernel_launch(void* const* d_in, const int* in_sizes, int n_in,
                              void* d_out, int out_size, void* d_ws, size_t ws_size,
                              hipStream_t stream)
{
    const float* x     = (const float*)d_in[0];
    const float* gamma = (const float*)d_in[1];
    const float* beta  = (const float*)d_in[2];
    const float* Wq    = (const float*)d_in[3];
    const float* bq    = (const float*)d_in[4];
    const float* Wk    = (const float*)d_in[5];
    const float* bk    = (const float*)d_in[6];
    const float* Wv    = (const float*)d_in[7];
    const float* bv    = (const float*)d_in[8];
    const float* Wo    = (const float*)d_in[9];
    const float* bo    = (const float*)d_in[10];
    float* out = (float*)d_out;

    const size_t MiB = 1024 * 1024;
    const size_t CC = (size_t)C_ * C_;
    const size_t LC = (size_t)L_ * C_;             // 1M elems (2 MiB bf16)
    const size_t LL = (size_t)L_ * L_;             // 4M elems (8 MiB bf16)
    const size_t wbytes = 4 * CC * sizeof(short);  // 2 MiB

    // per batch: h_t 2 + qk_t 4 + v 2 + S 8 MiB + rowsum 8 KiB
    const size_t perb = 16 * MiB + L_ * sizeof(float);
    int nb = 1;
    for (int c = 8; c >= 1; c >>= 1)
        if (ws_size >= wbytes + (size_t)c * perb) { nb = c; break; }

    short* wq_b = (short*)d_ws;       // rows 0-511 Wq, 512-1023 Wk (contiguous)
    short* wv_b = wq_b + 2 * CC;
    short* wo_b = wv_b + CC;
    short* h_t  = wo_b + CC;
    short* qk_t = h_t + (size_t)nb * LC;
    short* v_   = qk_t + (size_t)nb * 2 * LC;
    short* S    = v_  + (size_t)nb * LC;
    float* rsum = (float*)(S + (size_t)nb * LL);
    short* a_t  = h_t;                              // h_t dead after v GEMM

    const long sLC = (long)LC;
    const long sLL = (long)LL;
    const float scale = 0.044194173824159216f;      // 1/sqrt(512)

    cvt_w<<<dim3(C_ * C_ / 1024, 4), 256, 0, stream>>>(Wq, Wk, Wv, Wo, wq_b);

    for (int b0 = 0; b0 < B_; b0 += nb) {
        const float* xb = x + (size_t)b0 * LC;
        float* outb = out + (size_t)b0 * LC;

        zero_f32<<<dim3(nb * L_ / 256), 256, 0, stream>>>(rsum);
        groupnorm_tr<<<dim3(nb * G_), 256, 0, stream>>>(xb, gamma, beta, h_t);

        // qk_t[l, 0..1023] = h_t[l,:]·[Wq;Wk]^T + [bq;bk]
        gemm_bt<128, 3, false, false, false, false><<<dim3(8, 16, nb), 256, 0, stream>>>(
            h_t, wq_b, qk_t, bq, bk, nullptr, nullptr,
            1024, 512, 512, 512, 1024, sLC, 0, 2 * sLC, 1.f);
        // v[c,l] = Wv·h^T + bv
        gemm_bt<128, 2, false, false, false, false><<<dim3(16, 4, nb), 256, 0, stream>>>(
            wv_b, h_t, v_, bv, nullptr, nullptr, nullptr,
            2048, 512, 512, 512, 2048, 0, sLC, sLC, 1.f);
        // P~[i,j] = exp(scale * q[i,:]·k[j,:]);  rowsum[i] += partials  (8-wave 256x128)
        gemm_bt<256, 0, false, false, true, false><<<dim3(16, 8, nb), 512, 0, stream>>>(
            qk_t, qk_t + 512, S, nullptr, nullptr, nullptr, rsum,
            2048, 512, 1024, 1024, 2048, 2 * sLC, 2 * sLC, sLL, scale);
        // a_t[i,c] = (sum_j P~[i,j] v[c,j]) / rowsum[i]
        gemm_bt<128, 0, false, false, false, true><<<dim3(4, 16, nb), 256, 0, stream>>>(
            S, v_, a_t, nullptr, nullptr, nullptr, rsum,
            512, 2048, 2048, 2048, 512, sLL, sLC, sLC, 1.f);
        // out[c,l] = x[c,l] + bo[c] + Wo·a^T   (fp32 out)
        gemm_bt<128, 2, true, true, false, false><<<dim3(16, 4, nb), 256, 0, stream>>>(
            wo_b, a_t, outb, bo, nullptr, xb, nullptr,
            2048, 512, 512, 512, 2048, 0, sLC, sLC, 1.f);
    }
}